// Round 9
// baseline (326.992 us; speedup 1.0000x reference)
//
#include <hip/hip_runtime.h>
#include <hip/hip_bf16.h>

typedef __hip_bfloat16 bf16;
typedef __bf16 bf16x8 __attribute__((ext_vector_type(8)));
typedef float f32x4 __attribute__((ext_vector_type(4)));

#define NEG_SLOPE 0.2f
#define F32_THRESH 256

// ---------------- helpers ----------------------------------------------------

__device__ __forceinline__ bool is_f32(const int* fcnt) { return *fcnt > F32_THRESH; }

__device__ __forceinline__ float ld_f(const void* p, long long i, bool f32) {
    return f32 ? ((const float*)p)[i] : __bfloat162float(((const bf16*)p)[i]);
}

__device__ __forceinline__ float b2f(unsigned hs) {
    return __uint_as_float(hs << 16);
}

__device__ __forceinline__ unsigned pack_bf2(float a, float b) {
    union { bf16 h[2]; unsigned u; } p;
    p.h[0] = __float2bfloat16(a);
    p.h[1] = __float2bfloat16(b);
    return p.u;
}

__device__ __forceinline__ void load_lds16(const void* g, void* l) {
    __builtin_amdgcn_global_load_lds(
        (const __attribute__((address_space(1))) void*)g,
        (__attribute__((address_space(3))) void*)l, 16, 0, 0);
}

// feature-vector fragment per lane: 8 bf16 (uint4) or 2 bf16 (unsigned)
template <int CPL> struct FV;
template <> struct FV<8> {
    uint4 v;
    __device__ __forceinline__ void load(const bf16* p) { v = *(const uint4*)p; }
    __device__ __forceinline__ void fma(float* acc, float w) const {
        unsigned uu[4] = {v.x, v.y, v.z, v.w};
#pragma unroll
        for (int q = 0; q < 4; q++) {
            acc[2 * q] += w * b2f(uu[q] & 0xFFFFu);
            acc[2 * q + 1] += w * b2f(uu[q] >> 16);
        }
    }
};
template <> struct FV<2> {
    unsigned v;
    __device__ __forceinline__ void load(const bf16* p) { v = *(const unsigned*)p; }
    __device__ __forceinline__ void fma(float* acc, float w) const {
        acc[0] += w * b2f(v & 0xFFFFu);
        acc[1] += w * b2f(v >> 16);
    }
};

// ---------------- probe: dtype sniff + int-width detect ---------------------

__global__ void k_probe(const unsigned* xw, long long nw, const int* idx, int n_half,
                        int* cnt, int* iflag) {
    long long t = blockIdx.x * (long long)blockDim.x + threadIdx.x;
    long long stride = (long long)gridDim.x * blockDim.x;
    int c = 0;
    for (long long i = t; i < nw; i += stride)
        if ((xw[i] & 0x7F80u) == 0x7F80u) c++;
    if (c) atomicAdd(cnt, c);
    int any = 0;
    for (long long i = t; i < n_half; i += stride)
        if (idx[2 * i + 1] != 0) any = 1;
    if (any) atomicOr(iflag, 1);
}

// ---------------- CSR build (hardened) --------------------------------------

__device__ __forceinline__ int edge_val(const void* idx, long long i, int is64) {
    return is64 ? (int)((const long long*)idx)[i] : ((const int*)idx)[i];
}

__global__ void k_count(const void* idx, const int* iflag, int E0, int N, int* deg) {
    int e = blockIdx.x * blockDim.x + threadIdx.x;
    if (e >= E0 + N) return;
    int is64 = (*iflag == 0);
    int d = (e < E0) ? edge_val(idx, (long long)E0 + e, is64) : (e - E0);
    if ((unsigned)d >= (unsigned)N) d = 0;
    atomicAdd(&deg[d], 1);
}

__global__ __launch_bounds__(1024) void k_scan(const int* deg, int* rowptr, int N) {
    __shared__ int part[1024];
    int t = threadIdx.x;
    int chunk = (N + 1023) / 1024;
    int s = t * chunk, e = min(N, s + chunk);
    int sum = 0;
    for (int i = s; i < e; i++) sum += deg[i];
    part[t] = sum;
    __syncthreads();
    for (int off = 1; off < 1024; off <<= 1) {
        int v = (t >= off) ? part[t - off] : 0;
        __syncthreads();
        part[t] += v;
        __syncthreads();
    }
    int run = (t == 0) ? 0 : part[t - 1];
    for (int i = s; i < e; i++) { rowptr[i] = run; run += deg[i]; }
    if (t == 1023) rowptr[N] = part[1023];
}

__global__ void k_scatter(const void* idx, const int* iflag, int E0, int N,
                          const int* rowptr, int* cursor, int* csr_src) {
    int e = blockIdx.x * blockDim.x + threadIdx.x;
    if (e >= E0 + N) return;
    int is64 = (*iflag == 0);
    int s, d;
    if (e < E0) {
        s = edge_val(idx, e, is64);
        d = edge_val(idx, (long long)E0 + e, is64);
    } else {
        s = d = e - E0;
    }
    if ((unsigned)s >= (unsigned)N) s = 0;
    if ((unsigned)d >= (unsigned)N) d = 0;
    int pos = rowptr[d] + atomicAdd(&cursor[d], 1);
    if ((unsigned)pos < (unsigned)(E0 + N)) csr_src[pos] = s;
}

// ---------------- fused prep: tobf16 / tail pad / W transposes / hagg pad ---

__global__ void k_prep(const void* x, const int* fcnt, bf16* xb, bf16* xtail,
                       const void* W1, bf16* W1t, const void* W2, bf16* W2t,
                       bf16* hpad, int hpad_elems, int N, int K, int C1, int C2,
                       int R0, long long n_valid, long long n_total) {
    const int b = blockIdx.x;
    const int tid = threadIdx.x;
    const bool f32 = is_f32(fcnt);
    if (b < 512) {
        if (!f32) return;
        long long n8 = n_total / 8;
        for (long long i = (long long)b * 256 + tid; i < n8; i += 512LL * 256) {
            long long base = i * 8;
            uint4 out;
            if (base + 8 <= n_valid) {
                const float4* s4 = (const float4*)x;
                float4 x0 = s4[i * 2], x1 = s4[i * 2 + 1];
                out.x = pack_bf2(x0.x, x0.y);
                out.y = pack_bf2(x0.z, x0.w);
                out.z = pack_bf2(x1.x, x1.y);
                out.w = pack_bf2(x1.z, x1.w);
            } else {
                bf16 tmp[8];
#pragma unroll
                for (int j = 0; j < 8; j++) {
                    long long k = base + j;
                    tmp[j] = (k < n_valid) ? __float2bfloat16(ld_f(x, k, true))
                                           : __float2bfloat16(0.f);
                }
                out = *(uint4*)tmp;
            }
            ((uint4*)xb)[i] = out;
        }
    } else if (b < 528) {
        int total = 128 * K;
        for (int i = (b - 512) * 256 + tid; i < total; i += 16 * 256) {
            int r = i / K;
            long long src = (long long)(R0 + r) * K + (i - r * K);
            xtail[i] = (R0 + r < N) ? __float2bfloat16(ld_f(x, src, f32))
                                    : __float2bfloat16(0.f);
        }
    } else if (b < 656) {
        int total = K * C1;
        for (int i = (b - 528) * 256 + tid; i < total; i += 128 * 256) {
            int k = i / C1, n = i - k * C1;
            W1t[(size_t)n * K + k] = __float2bfloat16(ld_f(W1, i, f32));
        }
    } else if (b < 688) {
        int total = C1 * C2;
        for (int i = (b - 656) * 256 + tid; i < total; i += 32 * 256) {
            int k = i / C2, n = i - k * C2;
            W2t[(size_t)n * C1 + k] = __float2bfloat16(ld_f(W2, i, f32));
        }
    } else {
        for (int i = (b - 688) * 256 + tid; i < hpad_elems; i += 16 * 256)
            hpad[i] = __float2bfloat16(0.f);
    }
}

// ---------------- MFMA GEMM with fused attention-logit epilogue -------------
// C[M,Nn] = A @ Bt^T. After the C-store, each block reduces its accumulator
// against a_src/a_dst (cols of one head) and atomicAdds per-row partials into
// als/ald (zero-initialized). gemm1: BN=128 -> one block per (rowblock, head),
// no contention. gemm2: BN=64 -> 2-way contention.

template <int BN, bool SEL, int H>
__global__ __launch_bounds__(256) void k_gemm(const void* Araw, const bf16* Aconv,
                                              const bf16* Atail, const int* fcnt,
                                              const bf16* __restrict__ Bt,
                                              bf16* __restrict__ C,
                                              const void* a_s, const void* a_d,
                                              float* __restrict__ als,
                                              float* __restrict__ ald,
                                              int M, int Nn, int K, int nfull) {
    constexpr int BM = 128, BK = 32;
    constexpr int NT = BN / 32;
    const int m0 = blockIdx.x * BM;
    const int n0 = blockIdx.y * BN;
    __shared__ __bf16 As[BM][BK];
    __shared__ __bf16 Bs[BN][BK];
    const int tid = threadIdx.x;
    const int wave = tid >> 6;
    const int lane = tid & 63;
    const int wm = (wave & 1) * 64;
    const int wn = (wave >> 1) * (NT * 16);
    const int lm = lane & 15;
    const int quad = lane >> 4;
    const int srow = tid >> 2;
    const int scol = (tid & 3) * 8;

    f32x4 acc[4][NT];
#pragma unroll
    for (int mt = 0; mt < 4; mt++)
#pragma unroll
        for (int nt = 0; nt < NT; nt++) acc[mt][nt] = (f32x4){0.f, 0.f, 0.f, 0.f};

    const bf16* Abase;
    int arow0;
    if (SEL) {
        const bf16* Asel = is_f32(fcnt) ? Aconv : (const bf16*)Araw;
        if ((int)blockIdx.x < nfull) { Abase = Asel; arow0 = m0; }
        else { Abase = Atail; arow0 = 0; }
    } else {
        Abase = (const bf16*)Araw;
        arow0 = m0;
    }

    const char* Ab = (const char*)(Abase + (size_t)(arow0 + srow) * K + scol);
    const char* Bb = (const char*)(Bt + (size_t)(n0 + srow) * K + scol);
    char* ldsA = (char*)&As[0][0] + wave * 1024;
    char* ldsB = (char*)&Bs[0][0] + wave * 1024;
    const size_t rstep = (size_t)64 * K * 2;

    for (int k0 = 0; k0 < K; k0 += BK) {
        __syncthreads();
        const size_t kb = (size_t)k0 * 2;
        load_lds16(Ab + kb, ldsA);
        load_lds16(Ab + kb + rstep, ldsA + 4096);
        load_lds16(Bb + kb, ldsB);
        if (BN == 128) load_lds16(Bb + kb + rstep, ldsB + 4096);
        __syncthreads();
        bf16x8 af[4], bfv[NT];
#pragma unroll
        for (int mt = 0; mt < 4; mt++)
            af[mt] = *(const bf16x8*)&As[wm + mt * 16 + lm][quad * 8];
#pragma unroll
        for (int nt = 0; nt < NT; nt++)
            bfv[nt] = *(const bf16x8*)&Bs[wn + nt * 16 + lm][quad * 8];
#pragma unroll
        for (int mt = 0; mt < 4; mt++)
#pragma unroll
            for (int nt = 0; nt < NT; nt++)
                acc[mt][nt] = __builtin_amdgcn_mfma_f32_16x16x32_bf16(
                    af[mt], bfv[nt], acc[mt][nt], 0, 0, 0);
    }

#pragma unroll
    for (int mt = 0; mt < 4; mt++) {
        int rb = m0 + wm + mt * 16 + quad * 4;
#pragma unroll
        for (int nt = 0; nt < NT; nt++) {
            int col = n0 + wn + nt * 16 + lm;
#pragma unroll
            for (int r = 0; r < 4; r++) {
                int row = rb + r;
                if (row < M) C[(size_t)row * Nn + col] = __float2bfloat16(acc[mt][nt][r]);
            }
        }
    }

    // fused attention-logit partials: al[row,head] += sum_col acc*a[col]
    const bool f32 = is_f32(fcnt);
    float sa_[NT], sd_[NT];
#pragma unroll
    for (int nt = 0; nt < NT; nt++) {
        int col = n0 + wn + nt * 16 + lm;  // also the flat a-index (H*Ch layout)
        sa_[nt] = ld_f(a_s, col, f32);
        sd_[nt] = ld_f(a_d, col, f32);
    }
    const int head = (H == 4) ? (n0 >> 7) : 0;
#pragma unroll
    for (int mt = 0; mt < 4; mt++) {
#pragma unroll
        for (int r = 0; r < 4; r++) {
            float ps_ = 0.f, pd_ = 0.f;
#pragma unroll
            for (int nt = 0; nt < NT; nt++) {
                float v = acc[mt][nt][r];
                ps_ += v * sa_[nt];
                pd_ += v * sd_[nt];
            }
#pragma unroll
            for (int off = 1; off < 16; off <<= 1) {
                ps_ += __shfl_xor(ps_, off, 64);
                pd_ += __shfl_xor(pd_, off, 64);
            }
            int row = m0 + wm + mt * 16 + quad * 4 + r;
            if (lm == 0 && row < M) {
                atomicAdd(&als[(size_t)row * H + head], ps_);
                atomicAdd(&ald[(size_t)row * H + head], pd_);
            }
        }
    }
}

// ---------------- per-dst aggregation (block-per-node, staged weights) ------
// Stage phase: 64-edge chunk's exp weights computed edge x head-parallel
// (1 exp/thread, no redundancy) into LDS. Gather phase: edges split across
// the 4 waves; each wave covers all C channels (uint4/dword gathers).
// Denominator: per-wave psum of its own edges' weights -> tiny LDS reduce.

template <int C, int H, bool ELU, bool DYN_OUT>
__global__ __launch_bounds__(256) void k_agg(
    const bf16* __restrict__ feat, const float* __restrict__ als,
    const float* __restrict__ ald, const int* __restrict__ rowptr,
    const int* __restrict__ csr_src, const void* bias, const int* fcnt,
    void* outp, int N, int E) {
    constexpr int CPL = C / 64;        // channels per lane (wave covers all C)
    constexpr int Ch = C / H;
    constexpr int WST = (H == 4) ? 5 : 1;  // s_w stride (pad to break banks)
    const int n = blockIdx.x;
    const int tid = threadIdx.x;
    const int wave = tid >> 6;
    const int lane = tid & 63;
    const int c0 = lane * CPL;
    const int head = c0 / Ch;          // H=4: lane/16 ; H=1: 0

    __shared__ float red[4][C];
    __shared__ float s_w[64 * WST];
    __shared__ int s_src[64];
    __shared__ float ps[4][H];

    int start = rowptr[n];
    if (start < 0) start = 0;
    int end = rowptr[n + 1];
    if (end > E) end = E;
    int deg = end - start;
    if (deg < 0) deg = 0;

    float acc[CPL] = {};
    float psum = 0.f;

    for (int base = 0; base < deg; base += 64) {
        int cnt = min(64, deg - base);
        __syncthreads();  // protect s_* from previous chunk's readers
        if (H == 4) {
            int e_ = tid & 63, h_ = tid >> 6;
            if (e_ < cnt) {
                int s = csr_src[start + base + e_];
                if ((unsigned)s >= (unsigned)N) s = 0;
                if (h_ == 0) s_src[e_] = s;
                float l = als[(size_t)s * 4 + h_] + ald[(size_t)n * 4 + h_];
                l = l > 0.f ? l : NEG_SLOPE * l;
                s_w[e_ * 5 + h_] = __expf(fminf(l, 60.f));
            }
        } else {
            if (tid < cnt) {
                int s = csr_src[start + base + tid];
                if ((unsigned)s >= (unsigned)N) s = 0;
                s_src[tid] = s;
                float l = als[s] + ald[n];
                l = l > 0.f ? l : NEG_SLOPE * l;
                s_w[tid] = __expf(fminf(l, 60.f));
            }
        }
        __syncthreads();
        // gather: edges split across waves; LDS reads are broadcasts
#pragma unroll 4
        for (int e = wave; e < cnt; e += 4) {
            int s = s_src[e];
            float wl = (H == 4) ? s_w[e * 5 + head] : s_w[e];
            psum += wl;
            FV<CPL> f;
            f.load(feat + (size_t)s * C + c0);
            f.fma(acc, wl);
        }
    }

    // cross-wave combine
#pragma unroll
    for (int j = 0; j < CPL; j++) red[wave][c0 + j] = acc[j];
    if ((lane & 15) == 0) ps[wave][head] = psum;  // H4: lanes 0/16/32/48 -> heads
    __syncthreads();

    const bool f32 = is_f32(fcnt);
    for (int c = tid; c < C; c += 256) {
        int h = c / Ch;
        float sv = 0.f;
        float dn = 1e-16f;
#pragma unroll
        for (int w2 = 0; w2 < 4; w2++) {
            sv += red[w2][c];
            dn += ps[w2][h];
        }
        float v = sv / dn + ld_f(bias, c, f32);
        if (ELU) v = v > 0.f ? v : expf(v) - 1.f;
        size_t oi = (size_t)n * C + c;
        if (DYN_OUT && f32) ((float*)outp)[oi] = v;
        else ((bf16*)outp)[oi] = __float2bfloat16(v);
    }
}

// ---------------- launch -----------------------------------------------------

extern "C" void kernel_launch(void* const* d_in, const int* in_sizes, int n_in,
                              void* d_out, int out_size, void* d_ws, size_t ws_size,
                              hipStream_t stream) {
    const int N = in_sizes[0] / 512;  // 20000
    const int K = 512;
    const int C1 = 512;
    const int C2 = 128;
    const int H1 = 4;
    const int E0 = in_sizes[1] / 2;   // 320000
    const int E = E0 + N;
    const int Mpad = (N + 127) / 128 * 128;  // 20096
    const int nfull = N / 128;               // full 128-row tiles

    const void* x_raw = d_in[0];
    const void* eidx = d_in[1];
    const void* W1 = d_in[2];
    const void* as1 = d_in[3];
    const void* ad1 = d_in[4];
    const void* b1 = d_in[5];
    const void* W2 = d_in[6];
    const void* as2 = d_in[7];
    const void* ad2 = d_in[8];
    const void* b2 = d_in[9];

    char* ws = (char*)d_ws;
    size_t off = 0;
    auto take = [&](size_t bytes) {
        size_t r = off;
        off += (bytes + 255) & ~(size_t)255;
        return r;
    };
    bf16* xb     = (bf16*)(ws + take((size_t)Mpad * K * 2));  // fp32 path; reused for h2
    bf16* xtail  = (bf16*)(ws + take((size_t)128 * K * 2));
    bf16* h1     = (bf16*)(ws + take((size_t)N * C1 * 2));
    bf16* hagg   = (bf16*)(ws + take((size_t)Mpad * C1 * 2));
    bf16* W1t    = (bf16*)(ws + take((size_t)K * C1 * 2));
    bf16* W2t    = (bf16*)(ws + take((size_t)C1 * C2 * 2));
    int* rowptr  = (int*)(ws + take((size_t)(N + 1) * 4));
    int* csr_src = (int*)(ws + take((size_t)E * 4));
    // contiguous zero-init region: deg(N), cursor(N), al1s(4N), al1d(4N),
    // al2s(N), al2d(N), iflag, fcnt  -> (12N + 2) ints
    int* zbase   = (int*)(ws + take((size_t)(12 * N + 2) * 4));
    int* deg     = zbase;
    int* cursor  = zbase + N;
    float* al1s  = (float*)(zbase + 2 * N);
    float* al1d  = al1s + 4 * N;
    float* al2s  = al1d + 4 * N;
    float* al2d  = al2s + N;
    int* iflag   = zbase + 12 * N;
    int* fcnt    = zbase + 12 * N + 1;
    bf16* h2     = xb;  // alias: xb dead after gemm1
    if (off > ws_size) return;

    hipMemsetAsync(zbase, 0, (size_t)(12 * N + 2) * 4, stream);

    // probes (capped scans)
    long long nw = (long long)in_sizes[0] / 2;
    if (nw > (1 << 20)) nw = 1 << 20;
    int nh = E0 > (1 << 16) ? (1 << 16) : E0;
    k_probe<<<256, 256, 0, stream>>>((const unsigned*)x_raw, nw, (const int*)eidx, nh,
                                     fcnt, iflag);

    // CSR build
    k_count<<<(E + 255) / 256, 256, 0, stream>>>(eidx, iflag, E0, N, deg);
    k_scan<<<1, 1024, 0, stream>>>(deg, rowptr, N);
    k_scatter<<<(E + 255) / 256, 256, 0, stream>>>(eidx, iflag, E0, N, rowptr, cursor,
                                                   csr_src);

    // fused prep: x convert (fp32 only) + tail pad + W transposes + hagg pad
    k_prep<<<704, 256, 0, stream>>>(x_raw, fcnt, xb, xtail, W1, W1t, W2, W2t,
                                    hagg + (size_t)N * C1, (Mpad - N) * C1,
                                    N, K, C1, C2, nfull * 128,
                                    (long long)N * K, (long long)Mpad * K);

    // layer 1: gemm (+ fused al1) then aggregate
    dim3 g1(Mpad / 128, C1 / 128);
    k_gemm<128, true, 4><<<g1, 256, 0, stream>>>(x_raw, xb, xtail, fcnt, W1t, h1,
                                                 as1, ad1, al1s, al1d, N, C1, K, nfull);
    k_agg<512, 4, true, false><<<N, 256, 0, stream>>>(
        h1, al1s, al1d, rowptr, csr_src, b1, fcnt, hagg, N, E);

    // layer 2: gemm (+ fused al2) then aggregate
    dim3 g2(Mpad / 128, C2 / 64);
    k_gemm<64, false, 1><<<g2, 256, 0, stream>>>(hagg, nullptr, nullptr, fcnt, W2t, h2,
                                                 as2, ad2, al2s, al2d, N, C2, C1, 0);
    k_agg<128, 1, false, true><<<N, 256, 0, stream>>>(
        h2, al2s, al2d, rowptr, csr_src, b2, fcnt, d_out, N, E);
}